// Round 10
// baseline (3611.039 us; speedup 1.0000x reference)
//
#include <hip/hip_runtime.h>

#define N_NODES   50000
#define N_EDGES   800000
#define N_REL     6
#define N_LAYERS  8
#define DD        256
#define NUM_GRAPHS 512

#define NKEYS      (N_REL * N_NODES)
#define SCAN_T     256
#define SCAN_E     8
#define SCAN_CHUNK (SCAN_T * SCAN_E)
#define SCAN_NB    ((NKEYS + SCAN_CHUNK - 1) / SCAN_CHUNK)

typedef _Float16 h4 __attribute__((ext_vector_type(4)));
typedef _Float16 h8 __attribute__((ext_vector_type(8)));
typedef float    f4 __attribute__((ext_vector_type(4)));

__device__ __forceinline__ void atomAddF(float* p, float v) { unsafeAtomicAdd(p, v); }

// async global->LDS, 16B per lane. LDS dest = wave-uniform base + lane*16.
__device__ __forceinline__ void load_lds16(const void* g, void* l) {
    __builtin_amdgcn_global_load_lds(
        (const __attribute__((address_space(1))) uint32_t*)g,
        (__attribute__((address_space(3))) uint32_t*)l, 16, 0, 0);
}

// ---------------- encoder: h = x @ enc_W + enc_b, write hi/lo fp16 planes ---
__global__ __launch_bounds__(256) void enc_kernel(const float* __restrict__ x,
                                                  const float* __restrict__ W,
                                                  const float* __restrict__ b,
                                                  _Float16* __restrict__ Hhi,
                                                  _Float16* __restrict__ Hlo) {
    int n = blockIdx.x;
    int d = threadIdx.x;
    float s = b[d];
#pragma unroll
    for (int k = 0; k < 13; ++k) s = fmaf(x[n * 13 + k], W[k * 256 + d], s);
    const _Float16 hi = (_Float16)s;
    Hhi[(size_t)n * DD + d] = hi;
    Hlo[(size_t)n * DD + d] = (_Float16)(s - (float)hi);
}

// ------------- weight split+transpose: rel_W/root_W(+I) -> WT[L][n][1792] ---
__global__ __launch_bounds__(256) void wsplit_rel_kernel(const float* __restrict__ relW,
                                                         const float* __restrict__ rootW,
                                                         _Float16* __restrict__ wthi,
                                                         _Float16* __restrict__ wtlo) {
    const size_t id = (size_t)blockIdx.x * 256 + threadIdx.x;
    if (id >= (size_t)N_LAYERS * 7 * 256 * 256) return;
    const int k = (int)(id & 255);
    const int n = (int)((id >> 8) & 255);
    const int g = (int)((id >> 16) % 7);
    const int L = (int)((id >> 16) / 7);
    float w = (g < 6)
        ? relW[(((size_t)L * 6 + g) * 256 + k) * 256 + n]
        : rootW[((size_t)L * 256 + k) * 256 + n];
    if (g == 6 && k == n) w += 1.0f;  // fold skip: h@(root+I) = h@root + h
    const _Float16 hi = (_Float16)w;
    const size_t o = ((size_t)L * 256 + n) * 1792 + (size_t)g * 256 + k;
    wthi[o] = hi;
    wtlo[o] = (_Float16)(w - (float)hi);
}

// generic [K][N] -> split planes [N][K]
__global__ __launch_bounds__(256) void wsplit_tr_kernel(const float* __restrict__ W,
                                                        _Float16* __restrict__ whi,
                                                        _Float16* __restrict__ wlo,
                                                        int K, int N) {
    const size_t id = (size_t)blockIdx.x * 256 + threadIdx.x;
    if (id >= (size_t)K * N) return;
    const int k = (int)(id % K), n = (int)(id / K);
    const float w = W[(size_t)k * N + n];
    const _Float16 hi = (_Float16)w;
    whi[(size_t)n * K + k] = hi;
    wlo[(size_t)n * K + k] = (_Float16)(w - (float)hi);
}

// split fp32 -> hi/lo planes
__global__ __launch_bounds__(256) void fsplit_kernel(const float* __restrict__ S,
                                                     _Float16* __restrict__ hi,
                                                     _Float16* __restrict__ lo, int total) {
    const int id = blockIdx.x * 256 + threadIdx.x;
    if (id >= total) return;
    const float v = S[id];
    const _Float16 h = (_Float16)v;
    hi[id] = h;
    lo[id] = (_Float16)(v - (float)h);
}

// ======= LDS-staged MFMA GEMM: 64x256 tile, BK=32, 4 waves (64 cols each) ===
// LDS 40KB (fp16 elems): Ah[0,2048) Al[2048,4096) Bh[4096,12288) Bl[12288,20480)
// 16B unit (row,slot): chunk c = slot ^ ((row>>1)&3) (XOR swizzle, stage=read).
// A = [agg planes (K_agg, plane stride N_NODES*DD) | h segment], row stride lda.
// B planes [n][ldb]; C row stride ldc; grid.y tiles N by 256.
// MODE 0: Cf = acc + bias                 (fp32)
// MODE 1: v = acc + Cf; prelu; full-row L2-norm -> Ohi/Olo  (bias already in Cf)
// MODE 2: relu(acc + bias) -> Ohi/Olo planes
// MODE 3: Cf += acc
// MODE 4: acc + bias -> Ohi/Olo planes
template <int MODE>
__global__ __launch_bounds__(256, 3) void gemm_lds(
    const _Float16* __restrict__ Ahi, const _Float16* __restrict__ Alo,
    const _Float16* __restrict__ Hhi, const _Float16* __restrict__ Hlo,
    const _Float16* __restrict__ Bhi, const _Float16* __restrict__ Blo,
    int lda, int ldb, int ldc, int boff_agg, int boff_h, int K_agg, int K_tot,
    float* __restrict__ Cf, _Float16* __restrict__ Ohi, _Float16* __restrict__ Olo,
    const float* __restrict__ bias, const float* __restrict__ pa, int M) {
    __shared__ _Float16 smem[20480];  // 40 KB
    const int lane = threadIdx.x & 63;
    const int wave = threadIdx.x >> 6;
    const int lm = lane & 15, lq = lane >> 4;
    const int mb = blockIdx.x * 64;
    const int nb = blockIdx.y * 256;

    int arow_g, a_c8;
    {
        const int u = wave * 64 + lane;          // 0..255: 64 rows x 4 slots
        const int row = u >> 2, slot = u & 3;
        int rg = mb + row; if (rg >= M) rg = M - 1;
        arow_g = rg;
        a_c8   = (slot ^ ((row >> 1) & 3)) * 8;
    }
    int brow_g[4], b_c8[4];
#pragma unroll
    for (int q = 0; q < 4; ++q) {
        const int u = q * 256 + wave * 64 + lane;  // 0..1023: 256 rows x 4 slots
        const int row = u >> 2, slot = u & 3;
        brow_g[q] = nb + row;
        b_c8[q]   = (slot ^ ((row >> 1) & 3)) * 8;
    }

    f4 acc[4][4];
#pragma unroll
    for (int i = 0; i < 4; ++i)
#pragma unroll
        for (int j = 0; j < 4; ++j) acc[i][j] = (f4){0.f, 0.f, 0.f, 0.f};

    for (int k0 = 0; k0 < K_tot; k0 += 32) {
        const _Float16 *pAh, *pAl;
        int acol, bcol;
        if (k0 < K_agg) {
            const size_t pb = (size_t)(k0 >> 8) * (size_t)N_NODES * DD;
            pAh = Ahi + pb; pAl = Alo + pb;
            acol = k0 & 255;
            bcol = boff_agg + k0;
        } else {
            pAh = Hhi; pAl = Hlo;
            acol = k0 - K_agg;
            bcol = boff_h + (k0 - K_agg);
        }

        __syncthreads();  // previous tile fully consumed
        {
            const size_t ga = (size_t)arow_g * lda + acol + a_c8;
            load_lds16(pAh + ga, smem + wave * 512);
            load_lds16(pAl + ga, smem + 2048 + wave * 512);
        }
#pragma unroll
        for (int q = 0; q < 4; ++q) {
            const size_t gb = (size_t)brow_g[q] * ldb + bcol + b_c8[q];
            const int eb = (q * 256 + wave * 64) * 8;
            load_lds16(Bhi + gb, smem + 4096 + eb);
            load_lds16(Blo + gb, smem + 12288 + eb);
        }
        __syncthreads();  // staging drained

        h8 ah[4], al[4], bh[4], bl[4];
#pragma unroll
        for (int i = 0; i < 4; ++i) {
            const int row  = i * 16 + lm;
            const int slot = lq ^ ((row >> 1) & 3);
            const int o    = (row * 4 + slot) * 8;
            ah[i] = *(const h8*)(smem + o);
            al[i] = *(const h8*)(smem + 2048 + o);
        }
#pragma unroll
        for (int j = 0; j < 4; ++j) {
            const int n    = wave * 64 + j * 16 + lm;
            const int slot = lq ^ ((n >> 1) & 3);
            const int o    = (n * 4 + slot) * 8;
            bh[j] = *(const h8*)(smem + 4096 + o);
            bl[j] = *(const h8*)(smem + 12288 + o);
        }
#pragma unroll
        for (int i = 0; i < 4; ++i)
#pragma unroll
            for (int j = 0; j < 4; ++j) {
                acc[i][j] = __builtin_amdgcn_mfma_f32_16x16x32_f16(ah[i], bh[j], acc[i][j], 0, 0, 0);
                acc[i][j] = __builtin_amdgcn_mfma_f32_16x16x32_f16(ah[i], bl[j], acc[i][j], 0, 0, 0);
                acc[i][j] = __builtin_amdgcn_mfma_f32_16x16x32_f16(al[i], bh[j], acc[i][j], 0, 0, 0);
            }
    }

    if (MODE == 0) {
#pragma unroll
        for (int i = 0; i < 4; ++i)
#pragma unroll
            for (int r = 0; r < 4; ++r) {
                const int row = mb + i * 16 + lq * 4 + r;
                if (row >= M) continue;
#pragma unroll
                for (int j = 0; j < 4; ++j) {
                    const int col = nb + wave * 64 + j * 16 + lm;
                    Cf[(size_t)row * ldc + col] = acc[i][j][r] + bias[col];
                }
            }
    } else if (MODE == 3) {
#pragma unroll
        for (int i = 0; i < 4; ++i)
#pragma unroll
            for (int r = 0; r < 4; ++r) {
                const int row = mb + i * 16 + lq * 4 + r;
                if (row >= M) continue;
#pragma unroll
                for (int j = 0; j < 4; ++j) {
                    const int col = nb + wave * 64 + j * 16 + lm;
                    Cf[(size_t)row * ldc + col] += acc[i][j][r];
                }
            }
    } else if (MODE == 2 || MODE == 4) {
#pragma unroll
        for (int i = 0; i < 4; ++i)
#pragma unroll
            for (int r = 0; r < 4; ++r) {
                const int row = mb + i * 16 + lq * 4 + r;
                if (row >= M) continue;
#pragma unroll
                for (int j = 0; j < 4; ++j) {
                    const int col = nb + wave * 64 + j * 16 + lm;
                    float v = acc[i][j][r] + bias[col];
                    if (MODE == 2) v = fmaxf(v, 0.f);
                    const _Float16 hi = (_Float16)v;
                    const size_t idx = (size_t)row * ldc + col;
                    Ohi[idx] = hi;
                    Olo[idx] = (_Float16)(v - (float)hi);
                }
            }
    } else {  // MODE 1: v = acc + Cf (bias already in Cf); prelu; row-norm
        float* shf = (float*)smem;  // [4][64]
        const float a = pa[0];
        __syncthreads();  // done with fp16 staging
#pragma unroll
        for (int i = 0; i < 4; ++i)
#pragma unroll
            for (int r = 0; r < 4; ++r) {
                const int rl  = i * 16 + lq * 4 + r;
                const int row = mb + rl;
                float rss = 0.f;
                if (row < M) {
#pragma unroll
                    for (int j = 0; j < 4; ++j) {
                        const int col = nb + wave * 64 + j * 16 + lm;
                        float v = acc[i][j][r] + Cf[(size_t)row * ldc + col];
                        v = v > 0.f ? v : a * v;
                        acc[i][j][r] = v;
                        rss = fmaf(v, v, rss);
                    }
                }
                rss += __shfl_xor(rss, 1, 64);
                rss += __shfl_xor(rss, 2, 64);
                rss += __shfl_xor(rss, 4, 64);
                rss += __shfl_xor(rss, 8, 64);
                if (lm == 0 && row < M) shf[wave * 64 + rl] = rss;
            }
        __syncthreads();
#pragma unroll
        for (int i = 0; i < 4; ++i)
#pragma unroll
            for (int r = 0; r < 4; ++r) {
                const int rl  = i * 16 + lq * 4 + r;
                const int row = mb + rl;
                if (row >= M) continue;
                const float tot = shf[rl] + shf[64 + rl] + shf[128 + rl] + shf[192 + rl];
                const float inv = 1.0f / fmaxf(sqrtf(tot), 1e-12f);
#pragma unroll
                for (int j = 0; j < 4; ++j) {
                    const int col = nb + wave * 64 + j * 16 + lm;
                    const float v = acc[i][j][r] * inv;
                    const _Float16 hi = (_Float16)v;
                    const size_t idx = (size_t)row * ldc + col;
                    Ohi[idx] = hi;
                    Olo[idx] = (_Float16)(v - (float)hi);
                }
            }
    }
}

// ================= CSR build: counting sort by key = rel*N_NODES + dst ======
__global__ __launch_bounds__(256) void hist_kernel(const int* __restrict__ dst,
                                                   const int* __restrict__ etype,
                                                   int* __restrict__ cnt) {
    const int e = blockIdx.x * 256 + threadIdx.x;
    if (e >= N_EDGES) return;
    atomicAdd(&cnt[etype[e] * N_NODES + dst[e]], 1);
}

__global__ __launch_bounds__(SCAN_T) void scan1_kernel(const int* __restrict__ cnt,
                                                       int* __restrict__ off,
                                                       int* __restrict__ bsum) {
    __shared__ int sh[SCAN_T];
    const int b = blockIdx.x, t = threadIdx.x;
    const int base = b * SCAN_CHUNK + t * SCAN_E;
    int pre[SCAN_E];
    int s = 0;
#pragma unroll
    for (int i = 0; i < SCAN_E; ++i) {
        const int x = (base + i < NKEYS) ? cnt[base + i] : 0;
        pre[i] = s;
        s += x;
    }
    sh[t] = s;
    __syncthreads();
    for (int d = 1; d < SCAN_T; d <<= 1) {
        const int x = (t >= d) ? sh[t - d] : 0;
        __syncthreads();
        sh[t] += x;
        __syncthreads();
    }
    const int toff = (t == 0) ? 0 : sh[t - 1];
#pragma unroll
    for (int i = 0; i < SCAN_E; ++i)
        if (base + i < NKEYS) off[base + i] = toff + pre[i];
    if (t == SCAN_T - 1) bsum[b] = sh[SCAN_T - 1];
}

__global__ __launch_bounds__(SCAN_T) void scan2_kernel(int* __restrict__ bsum, int n) {
    __shared__ int sh[SCAN_T];
    const int t = threadIdx.x;
    const int base = t * SCAN_E;
    int pre[SCAN_E];
    int s = 0;
#pragma unroll
    for (int i = 0; i < SCAN_E; ++i) {
        const int x = (base + i < n) ? bsum[base + i] : 0;
        pre[i] = s;
        s += x;
    }
    sh[t] = s;
    __syncthreads();
    for (int d = 1; d < SCAN_T; d <<= 1) {
        const int x = (t >= d) ? sh[t - d] : 0;
        __syncthreads();
        sh[t] += x;
        __syncthreads();
    }
    const int toff = (t == 0) ? 0 : sh[t - 1];
#pragma unroll
    for (int i = 0; i < SCAN_E; ++i)
        if (base + i < n) bsum[base + i] = toff + pre[i];
}

__global__ __launch_bounds__(SCAN_T) void scan3_kernel(int* __restrict__ off,
                                                       const int* __restrict__ bsum) {
    const int b = blockIdx.x, t = threadIdx.x;
    const int add = bsum[b];
    const int base = b * SCAN_CHUNK + t * SCAN_E;
#pragma unroll
    for (int i = 0; i < SCAN_E; ++i)
        if (base + i < NKEYS) off[base + i] += add;
    if (b == 0 && t == 0) off[NKEYS] = N_EDGES;
}

__global__ __launch_bounds__(256) void csr_fill_kernel(const int* __restrict__ src,
                                                       const int* __restrict__ dst,
                                                       const int* __restrict__ etype,
                                                       int* __restrict__ cursor,
                                                       int* __restrict__ sorted_src) {
    const int e = blockIdx.x * 256 + threadIdx.x;
    if (e >= N_EDGES) return;
    const int key = etype[e] * N_NODES + dst[e];
    const int pos = atomicAdd(&cursor[key], 1);
    sorted_src[pos] = src[e];
}

// ---------- aggregation: one wave per (node, rel); 2 edges/iteration --------
__global__ __launch_bounds__(256) void agg_kernel(const _Float16* __restrict__ Hhi,
                                                  const _Float16* __restrict__ Hlo,
                                                  const int* __restrict__ off,
                                                  const int* __restrict__ isrc,
                                                  _Float16* __restrict__ agghi,
                                                  _Float16* __restrict__ agglo,
                                                  int rel0, int nrel) {
    const int p    = blockIdx.x * 4 + (threadIdx.x >> 6);
    const int lane = threadIdx.x & 63;
    const int half = lane >> 5, li = lane & 31;
    if (p >= nrel * N_NODES) return;
    const int pl   = p / N_NODES;
    const int node = p - pl * N_NODES;
    const int r    = rel0 + pl;
    const int s0 = off[r * N_NODES + node];
    const int s1 = off[r * N_NODES + node + 1];
    float a[8] = {0.f, 0.f, 0.f, 0.f, 0.f, 0.f, 0.f, 0.f};
    for (int e0 = s0; e0 < s1; e0 += 2) {
        const int e = e0 + half;
        if (e < s1) {
            const int s = isrc[e];
            const h8 vh = *(const h8*)(Hhi + (size_t)s * DD + li * 8);
            const h8 vl = *(const h8*)(Hlo + (size_t)s * DD + li * 8);
#pragma unroll
            for (int k = 0; k < 8; ++k) a[k] += (float)vh[k] + (float)vl[k];
        }
    }
#pragma unroll
    for (int k = 0; k < 8; ++k) a[k] += __shfl_xor(a[k], 32, 64);
    if (half == 0) {
        h8 oh, ol;
#pragma unroll
        for (int k = 0; k < 8; ++k) {
            oh[k] = (_Float16)a[k];
            ol[k] = (_Float16)(a[k] - (float)oh[k]);
        }
        const size_t o = ((size_t)pl * N_NODES + node) * DD + li * 8;
        *(h8*)(agghi + o) = oh;
        *(h8*)(agglo + o) = ol;
    }
}

// ---------------- pooled[batch[n]] += hi[n]+lo[n]  (batch sorted) -----------
__global__ __launch_bounds__(64) void pool_kernel(const _Float16* __restrict__ ghi,
                                                  const _Float16* __restrict__ glo,
                                                  const int* __restrict__ batch,
                                                  float* __restrict__ pooled) {
    const int c     = threadIdx.x;
    const int start = blockIdx.x * 128;
    const int end   = min(start + 128, N_NODES);
    int cur = batch[start];
    float4 acc = {0.f, 0.f, 0.f, 0.f};
    for (int n = start; n < end; ++n) {
        const int bn = batch[n];
        if (bn != cur) {
            float* p = pooled + (size_t)cur * DD + c * 4;
            atomAddF(p + 0, acc.x); atomAddF(p + 1, acc.y);
            atomAddF(p + 2, acc.z); atomAddF(p + 3, acc.w);
            acc = {0.f, 0.f, 0.f, 0.f};
            cur = bn;
        }
        const h4 vh = *(const h4*)(ghi + (size_t)n * DD + c * 4);
        const h4 vl = *(const h4*)(glo + (size_t)n * DD + c * 4);
        acc.x += (float)vh[0] + (float)vl[0];
        acc.y += (float)vh[1] + (float)vl[1];
        acc.z += (float)vh[2] + (float)vl[2];
        acc.w += (float)vh[3] + (float)vl[3];
    }
    float* p = pooled + (size_t)cur * DD + c * 4;
    atomAddF(p + 0, acc.x); atomAddF(p + 1, acc.y);
    atomAddF(p + 2, acc.z); atomAddF(p + 3, acc.w);
}

// ---------------- out = relu((z2hi+z2lo) @ out_W + out_b) -------------------
__global__ __launch_bounds__(64) void out_kernel(const _Float16* __restrict__ z2hi,
                                                 const _Float16* __restrict__ z2lo,
                                                 const float* __restrict__ W,
                                                 const float* __restrict__ b,
                                                 float* __restrict__ out) {
    const int g = blockIdx.x;
    const int t = threadIdx.x;
    float s = 0.f;
#pragma unroll
    for (int j = 0; j < 8; ++j) {
        const int idx = t + 64 * j;
        const float z = (float)z2hi[(size_t)g * 512 + idx] + (float)z2lo[(size_t)g * 512 + idx];
        s = fmaf(z, W[idx], s);
    }
#pragma unroll
    for (int off = 32; off; off >>= 1) s += __shfl_xor(s, off, 64);
    if (t == 0) {
        const float v = s + b[0];
        out[g] = v > 0.f ? v : 0.f;
    }
}

extern "C" void kernel_launch(void* const* d_in, const int* in_sizes, int n_in,
                              void* d_out, int out_size, void* d_ws, size_t ws_size,
                              hipStream_t stream) {
    const float* x       = (const float*)d_in[0];
    const int*   eidx    = (const int*)d_in[1];
    const int*   etype   = (const int*)d_in[2];
    const int*   batch   = (const int*)d_in[3];
    const float* enc_W   = (const float*)d_in[4];
    const float* enc_b   = (const float*)d_in[5];
    const float* prelu_a = (const float*)d_in[6];
    const float* rel_W   = (const float*)d_in[7];
    const float* root_W  = (const float*)d_in[8];
    const float* conv_b  = (const float*)d_in[9];
    const float* gp_W1   = (const float*)d_in[10];
    const float* gp_b1   = (const float*)d_in[11];
    const float* gp_W2   = (const float*)d_in[12];
    const float* gp_b2   = (const float*)d_in[13];
    const float* fc_W1   = (const float*)d_in[14];
    const float* fc_b1   = (const float*)d_in[15];
    const float* fc_W2   = (const float*)d_in[16];
    const float* fc_b2   = (const float*)d_in[17];
    const float* out_W   = (const float*)d_in[18];
    const float* out_b   = (const float*)d_in[19];
    float* out = (float*)d_out;

    // workspace arena — HARD BUDGET: 236 MB ran (R8), 277 MB crashed (R4/R9).
    // This layout: 51.2+25.6+25.6+51.2+51.2+7.3+7.3+~0.5+~3+~5 ≈ 233 MB. OK.
    uint8_t* wp = (uint8_t*)d_ws;
    auto alloc = [&](size_t bytes) {
        void* r = (void*)wp;
        wp += (bytes + 255) & ~(size_t)255;
        return r;
    };
    float*    base   = (float*)alloc((size_t)N_NODES * DD * 4);          // 51.2 MB
    _Float16* Hhi    = (_Float16*)alloc((size_t)N_NODES * DD * 2);       // 25.6 MB
    _Float16* Hlo    = (_Float16*)alloc((size_t)N_NODES * DD * 2);       // 25.6 MB
    _Float16* agghi  = (_Float16*)alloc((size_t)2 * N_NODES * DD * 2);   // 51.2 MB (2 planes)
    _Float16* agglo  = (_Float16*)alloc((size_t)2 * N_NODES * DD * 2);   // 51.2 MB
    _Float16* wthi   = (_Float16*)alloc((size_t)N_LAYERS * 256 * 1792 * 2);  // 7.3 MB
    _Float16* wtlo   = (_Float16*)alloc((size_t)N_LAYERS * 256 * 1792 * 2);  // 7.3 MB
    _Float16* wtg1hi = (_Float16*)alloc((size_t)256 * 256 * 2);
    _Float16* wtg1lo = (_Float16*)alloc((size_t)256 * 256 * 2);
    _Float16* wtg2hi = (_Float16*)alloc((size_t)256 * 256 * 2);
    _Float16* wtg2lo = (_Float16*)alloc((size_t)256 * 256 * 2);
    _Float16* wtf1hi = (_Float16*)alloc((size_t)1024 * 256 * 2);
    _Float16* wtf1lo = (_Float16*)alloc((size_t)1024 * 256 * 2);
    _Float16* wtf2hi = (_Float16*)alloc((size_t)512 * 1024 * 2);
    _Float16* wtf2lo = (_Float16*)alloc((size_t)512 * 1024 * 2);
    float*    pooled = (float*)alloc((size_t)NUM_GRAPHS * DD * 4);
    _Float16* phi    = (_Float16*)alloc((size_t)NUM_GRAPHS * DD * 2);
    _Float16* plo    = (_Float16*)alloc((size_t)NUM_GRAPHS * DD * 2);
    _Float16* z1hi   = (_Float16*)alloc((size_t)NUM_GRAPHS * 1024 * 2);
    _Float16* z1lo   = (_Float16*)alloc((size_t)NUM_GRAPHS * 1024 * 2);
    _Float16* z2hi   = (_Float16*)alloc((size_t)NUM_GRAPHS * 512 * 2);
    _Float16* z2lo   = (_Float16*)alloc((size_t)NUM_GRAPHS * 512 * 2);
    int*      ioff   = (int*)alloc((size_t)(NKEYS + 1) * 4);
    int*      icur   = (int*)alloc((size_t)NKEYS * 4);
    int*      ibsum  = (int*)alloc(256 * 4);
    int*      isrc   = (int*)alloc((size_t)N_EDGES * 4);

    const int* src = eidx;
    const int* dst = eidx + N_EDGES;

    // ---- weight prep ----
    const size_t wtot = (size_t)N_LAYERS * 7 * 256 * 256;
    wsplit_rel_kernel<<<(int)((wtot + 255) / 256), 256, 0, stream>>>(rel_W, root_W, wthi, wtlo);
    wsplit_tr_kernel<<<256, 256, 0, stream>>>(gp_W1, wtg1hi, wtg1lo, 256, 256);
    wsplit_tr_kernel<<<256, 256, 0, stream>>>(gp_W2, wtg2hi, wtg2lo, 256, 256);
    wsplit_tr_kernel<<<1024, 256, 0, stream>>>(fc_W1, wtf1hi, wtf1lo, 256, 1024);
    wsplit_tr_kernel<<<2048, 256, 0, stream>>>(fc_W2, wtf2hi, wtf2lo, 1024, 512);

    // ---- CSR build ----
    hipMemsetAsync(icur, 0, (size_t)NKEYS * sizeof(int), stream);
    const int eb = (N_EDGES + 255) / 256;
    hist_kernel<<<eb, 256, 0, stream>>>(dst, etype, icur);
    scan1_kernel<<<SCAN_NB, SCAN_T, 0, stream>>>(icur, ioff, ibsum);
    scan2_kernel<<<1, SCAN_T, 0, stream>>>(ibsum, SCAN_NB);
    scan3_kernel<<<SCAN_NB, SCAN_T, 0, stream>>>(ioff, ibsum);
    hipMemcpyAsync(icur, ioff, (size_t)NKEYS * sizeof(int), hipMemcpyDeviceToDevice, stream);
    csr_fill_kernel<<<eb, 256, 0, stream>>>(src, dst, etype, icur, isrc);

    // ---- encoder ----
    enc_kernel<<<N_NODES, 256, 0, stream>>>(x, enc_W, enc_b, Hhi, Hlo);

    const dim3 gG((N_NODES + 63) / 64, 1);    // 782 x 1
    const int  aggb = (2 * N_NODES + 3) / 4;  // 2 rels per agg pass

    for (int L = 0; L < N_LAYERS; ++L) {
        const _Float16* Bh = wthi + (size_t)L * 256 * 1792;
        const _Float16* Bl = wtlo + (size_t)L * 256 * 1792;
        // GEMM1: rels 0,1 (K_agg=512) + h seg (root+I, K=256) + conv_b -> base
        agg_kernel<<<aggb, 256, 0, stream>>>(Hhi, Hlo, ioff, isrc, agghi, agglo, 0, 2);
        gemm_lds<0><<<gG, 256, 0, stream>>>(agghi, agglo, Hhi, Hlo, Bh, Bl,
                                            256, 1792, 256, 0, 1536, 512, 768,
                                            base, nullptr, nullptr,
                                            conv_b + L * DD, nullptr, N_NODES);
        // GEMM2: rels 2,3 accumulate into base
        agg_kernel<<<aggb, 256, 0, stream>>>(Hhi, Hlo, ioff, isrc, agghi, agglo, 2, 2);
        gemm_lds<3><<<gG, 256, 0, stream>>>(agghi, agglo, nullptr, nullptr, Bh, Bl,
                                            256, 1792, 256, 512, 0, 512, 512,
                                            base, nullptr, nullptr,
                                            nullptr, nullptr, N_NODES);
        // GEMM3: rels 4,5 + base; fused PReLU + row-norm -> new h planes
        agg_kernel<<<aggb, 256, 0, stream>>>(Hhi, Hlo, ioff, isrc, agghi, agglo, 4, 2);
        gemm_lds<1><<<gG, 256, 0, stream>>>(agghi, agglo, nullptr, nullptr, Bh, Bl,
                                            256, 1792, 256, 1024, 0, 512, 512,
                                            base, Hhi, Hlo,
                                            nullptr, prelu_a, N_NODES);
    }

    // gp1 = relu(h @ gp_W1 + gp_b1) -> planes (agg plane 0)
    gemm_lds<2><<<gG, 256, 0, stream>>>(nullptr, nullptr, Hhi, Hlo, wtg1hi, wtg1lo,
                                        256, 256, 256, 0, 0, 0, 256,
                                        nullptr, agghi, agglo, gp_b1, nullptr, N_NODES);
    // gp2 = gp1 @ gp_W2 + gp_b2 -> planes (agg plane 1)
    gemm_lds<4><<<gG, 256, 0, stream>>>(nullptr, nullptr, agghi, agglo, wtg2hi, wtg2lo,
                                        256, 256, 256, 0, 0, 0, 256,
                                        nullptr, agghi + (size_t)N_NODES * DD,
                                        agglo + (size_t)N_NODES * DD, gp_b2, nullptr, N_NODES);

    hipMemsetAsync(pooled, 0, (size_t)NUM_GRAPHS * DD * sizeof(float), stream);
    pool_kernel<<<(N_NODES + 127) / 128, 64, 0, stream>>>(
        agghi + (size_t)N_NODES * DD, agglo + (size_t)N_NODES * DD, batch, pooled);
    fsplit_kernel<<<(NUM_GRAPHS * DD + 255) / 256, 256, 0, stream>>>(
        pooled, phi, plo, NUM_GRAPHS * DD);

    // z1 = relu(pooled @ fc_W1 + fc_b1): M=512, K=256, N=1024
    gemm_lds<2><<<dim3(8, 4), 256, 0, stream>>>(nullptr, nullptr, phi, plo, wtf1hi, wtf1lo,
                                                256, 256, 1024, 0, 0, 0, 256,
                                                nullptr, z1hi, z1lo, fc_b1, nullptr,
                                                NUM_GRAPHS);
    // z2 = relu(z1 @ fc_W2 + fc_b2): M=512, K=1024, N=512
    gemm_lds<2><<<dim3(8, 2), 256, 0, stream>>>(nullptr, nullptr, z1hi, z1lo, wtf2hi, wtf2lo,
                                                1024, 1024, 512, 0, 0, 0, 1024,
                                                nullptr, z2hi, z2lo, fc_b2, nullptr,
                                                NUM_GRAPHS);
    out_kernel<<<NUM_GRAPHS, 64, 0, stream>>>(z2hi, z2lo, out_W, out_b, out);
}

// Round 11
// 3224.899 us; speedup vs baseline: 1.1197x; 1.1197x over previous
//
#include <hip/hip_runtime.h>

#define N_NODES   50000
#define N_EDGES   800000
#define N_REL     6
#define N_LAYERS  8
#define DD        256
#define NUM_GRAPHS 512

#define NKEYS      (N_REL * N_NODES)
#define SCAN_T     256
#define SCAN_E     8
#define SCAN_CHUNK (SCAN_T * SCAN_E)
#define SCAN_NB    ((NKEYS + SCAN_CHUNK - 1) / SCAN_CHUNK)

typedef _Float16 h4 __attribute__((ext_vector_type(4)));
typedef _Float16 h8 __attribute__((ext_vector_type(8)));
typedef float    f4 __attribute__((ext_vector_type(4)));

__device__ __forceinline__ void atomAddF(float* p, float v) { unsafeAtomicAdd(p, v); }

// async global->LDS, 16B per lane. LDS dest = wave-uniform base + lane*16.
__device__ __forceinline__ void load_lds16(const void* g, void* l) {
    __builtin_amdgcn_global_load_lds(
        (const __attribute__((address_space(1))) uint32_t*)g,
        (__attribute__((address_space(3))) uint32_t*)l, 16, 0, 0);
}

// ---------------- encoder: h = x @ enc_W + enc_b, write hi/lo fp16 planes ---
__global__ __launch_bounds__(256) void enc_kernel(const float* __restrict__ x,
                                                  const float* __restrict__ W,
                                                  const float* __restrict__ b,
                                                  _Float16* __restrict__ Hhi,
                                                  _Float16* __restrict__ Hlo) {
    int n = blockIdx.x;
    int d = threadIdx.x;
    float s = b[d];
#pragma unroll
    for (int k = 0; k < 13; ++k) s = fmaf(x[n * 13 + k], W[k * 256 + d], s);
    const _Float16 hi = (_Float16)s;
    Hhi[(size_t)n * DD + d] = hi;
    Hlo[(size_t)n * DD + d] = (_Float16)(s - (float)hi);
}

// ------------- weight split+transpose: rel_W/root_W(+I) -> WT[L][n][1792] ---
__global__ __launch_bounds__(256) void wsplit_rel_kernel(const float* __restrict__ relW,
                                                         const float* __restrict__ rootW,
                                                         _Float16* __restrict__ wthi,
                                                         _Float16* __restrict__ wtlo) {
    const size_t id = (size_t)blockIdx.x * 256 + threadIdx.x;
    if (id >= (size_t)N_LAYERS * 7 * 256 * 256) return;
    const int k = (int)(id & 255);
    const int n = (int)((id >> 8) & 255);
    const int g = (int)((id >> 16) % 7);
    const int L = (int)((id >> 16) / 7);
    float w = (g < 6)
        ? relW[(((size_t)L * 6 + g) * 256 + k) * 256 + n]
        : rootW[((size_t)L * 256 + k) * 256 + n];
    if (g == 6 && k == n) w += 1.0f;  // fold skip: h@(root+I) = h@root + h
    const _Float16 hi = (_Float16)w;
    const size_t o = ((size_t)L * 256 + n) * 1792 + (size_t)g * 256 + k;
    wthi[o] = hi;
    wtlo[o] = (_Float16)(w - (float)hi);
}

// generic [K][N] -> split planes [N][K]
__global__ __launch_bounds__(256) void wsplit_tr_kernel(const float* __restrict__ W,
                                                        _Float16* __restrict__ whi,
                                                        _Float16* __restrict__ wlo,
                                                        int K, int N) {
    const size_t id = (size_t)blockIdx.x * 256 + threadIdx.x;
    if (id >= (size_t)K * N) return;
    const int k = (int)(id % K), n = (int)(id / K);
    const float w = W[(size_t)k * N + n];
    const _Float16 hi = (_Float16)w;
    whi[(size_t)n * K + k] = hi;
    wlo[(size_t)n * K + k] = (_Float16)(w - (float)hi);
}

// split fp32 -> hi/lo planes
__global__ __launch_bounds__(256) void fsplit_kernel(const float* __restrict__ S,
                                                     _Float16* __restrict__ hi,
                                                     _Float16* __restrict__ lo, int total) {
    const int id = blockIdx.x * 256 + threadIdx.x;
    if (id >= total) return;
    const float v = S[id];
    const _Float16 h = (_Float16)v;
    hi[id] = h;
    lo[id] = (_Float16)(v - (float)h);
}

// ======= LDS-staged MFMA GEMM: 128x256 tile (R8-proven), BK=32 ==============
// 4 waves; wave = wm + 2*wn covers rows [wm*64,+64) x cols [wn*128,+128).
// LDS 48KB (fp16): Ah[0,4096) Al[4096,8192) Bh[8192,16384) Bl[16384,24576).
// 16B unit (row,slot): A 512 units/plane, B 1024 units/plane;
// chunk c = slot ^ ((row>>1)&3) (XOR swizzle, same stage & read).
// A = [agg planes (K_agg, plane stride N_NODES*DD, row stride lda) | h seg];
// B planes [n][ldb]; C row stride ldc; grid.y tiles N by 256.
// MODE 0: Cf = acc + bias
// MODE 1: v = acc + Cf; prelu; in-block full-row L2-norm -> Ohi/Olo (no bias)
// MODE 2: relu(acc + bias) -> Ohi/Olo planes
// MODE 3: Cf += acc
// MODE 4: acc + bias -> Ohi/Olo planes
template <int MODE>
__global__ __launch_bounds__(256, 2) void gemm_lds(
    const _Float16* __restrict__ Ahi, const _Float16* __restrict__ Alo,
    const _Float16* __restrict__ Hhi, const _Float16* __restrict__ Hlo,
    const _Float16* __restrict__ Bhi, const _Float16* __restrict__ Blo,
    int lda, int ldb, int ldc, int boff_agg, int boff_h, int K_agg, int K_tot,
    float* __restrict__ Cf, _Float16* __restrict__ Ohi, _Float16* __restrict__ Olo,
    const float* __restrict__ bias, const float* __restrict__ pa, int M) {
    __shared__ _Float16 smem[24576];  // 48 KB
    const int lane = threadIdx.x & 63;
    const int wave = threadIdx.x >> 6;
    const int lm = lane & 15, lq = lane >> 4;
    const int wm = wave & 1, wn = wave >> 1;
    const int mb = blockIdx.x * 128;
    const int nb = blockIdx.y * 256;

    f4 acc[4][8];
#pragma unroll
    for (int i = 0; i < 4; ++i)
#pragma unroll
        for (int j = 0; j < 8; ++j) acc[i][j] = (f4){0.f, 0.f, 0.f, 0.f};

    for (int k0 = 0; k0 < K_tot; k0 += 32) {
        const _Float16 *pAh, *pAl;
        int acol, bcol;
        if (k0 < K_agg) {
            const size_t pb = (size_t)(k0 >> 8) * (size_t)N_NODES * DD;
            pAh = Ahi + pb; pAl = Alo + pb;
            acol = k0 & 255;
            bcol = boff_agg + k0;
        } else {
            pAh = Hhi; pAl = Hlo;
            acol = k0 - K_agg;
            bcol = boff_h + (k0 - K_agg);
        }

        __syncthreads();  // previous tile fully consumed
#pragma unroll
        for (int q = 0; q < 12; ++q) {
            const int ub = (q * 4 + wave) * 64;  // 64-aligned unit base
            const int u  = ub + lane;
            const _Float16* gp;
            size_t ga;
            if (q < 4) {  // A planes (units 0..1023)
                const int v = u & 511, row = v >> 2, slot = v & 3;
                const int c = slot ^ ((row >> 1) & 3);
                int rg = mb + row; if (rg >= M) rg = M - 1;
                gp = (q < 2) ? pAh : pAl;
                ga = (size_t)rg * lda + acol + c * 8;
            } else {      // B planes (units 1024..3071)
                const int v = u & 1023, row = v >> 2, slot = v & 3;
                const int c = slot ^ ((row >> 1) & 3);
                gp = (q < 8) ? Bhi : Blo;
                ga = (size_t)(nb + row) * ldb + bcol + c * 8;
            }
            load_lds16(gp + ga, smem + (size_t)ub * 8);
        }
        __syncthreads();  // staging drained

        h8 ah[4], al[4], bh[8], bl[8];
#pragma unroll
        for (int i = 0; i < 4; ++i) {
            const int row  = wm * 64 + i * 16 + lm;
            const int slot = lq ^ ((row >> 1) & 3);
            const int o    = (row * 4 + slot) * 8;
            ah[i] = *(const h8*)(smem + o);
            al[i] = *(const h8*)(smem + 4096 + o);
        }
#pragma unroll
        for (int j = 0; j < 8; ++j) {
            const int n    = wn * 128 + j * 16 + lm;
            const int slot = lq ^ ((n >> 1) & 3);
            const int o    = (n * 4 + slot) * 8;
            bh[j] = *(const h8*)(smem + 8192 + o);
            bl[j] = *(const h8*)(smem + 16384 + o);
        }
#pragma unroll
        for (int i = 0; i < 4; ++i)
#pragma unroll
            for (int j = 0; j < 8; ++j) {
                acc[i][j] = __builtin_amdgcn_mfma_f32_16x16x32_f16(ah[i], bh[j], acc[i][j], 0, 0, 0);
                acc[i][j] = __builtin_amdgcn_mfma_f32_16x16x32_f16(ah[i], bl[j], acc[i][j], 0, 0, 0);
                acc[i][j] = __builtin_amdgcn_mfma_f32_16x16x32_f16(al[i], bh[j], acc[i][j], 0, 0, 0);
            }
    }

    if (MODE == 0) {
#pragma unroll
        for (int i = 0; i < 4; ++i)
#pragma unroll
            for (int r = 0; r < 4; ++r) {
                const int row = mb + wm * 64 + i * 16 + lq * 4 + r;
                if (row >= M) continue;
#pragma unroll
                for (int j = 0; j < 8; ++j) {
                    const int col = nb + wn * 128 + j * 16 + lm;
                    Cf[(size_t)row * ldc + col] = acc[i][j][r] + bias[col];
                }
            }
    } else if (MODE == 3) {
#pragma unroll
        for (int i = 0; i < 4; ++i)
#pragma unroll
            for (int r = 0; r < 4; ++r) {
                const int row = mb + wm * 64 + i * 16 + lq * 4 + r;
                if (row >= M) continue;
#pragma unroll
                for (int j = 0; j < 8; ++j) {
                    const int col = nb + wn * 128 + j * 16 + lm;
                    Cf[(size_t)row * ldc + col] += acc[i][j][r];
                }
            }
    } else if (MODE == 2 || MODE == 4) {
#pragma unroll
        for (int i = 0; i < 4; ++i)
#pragma unroll
            for (int r = 0; r < 4; ++r) {
                const int row = mb + wm * 64 + i * 16 + lq * 4 + r;
                if (row >= M) continue;
#pragma unroll
                for (int j = 0; j < 8; ++j) {
                    const int col = nb + wn * 128 + j * 16 + lm;
                    float v = acc[i][j][r] + bias[col];
                    if (MODE == 2) v = fmaxf(v, 0.f);
                    const _Float16 hi = (_Float16)v;
                    const size_t idx = (size_t)row * ldc + col;
                    Ohi[idx] = hi;
                    Olo[idx] = (_Float16)(v - (float)hi);
                }
            }
    } else {  // MODE 1: v = acc + Cf (bias already in Cf); prelu; row-norm
        float* shf = (float*)smem;  // [4][64] row partials
        const float a = pa[0];
        __syncthreads();  // done with fp16 staging
#pragma unroll
        for (int i = 0; i < 4; ++i)
#pragma unroll
            for (int r = 0; r < 4; ++r) {
                const int rl  = i * 16 + lq * 4 + r;       // 0..63 in wave's rows
                const int row = mb + wm * 64 + rl;
                float rss = 0.f;
                if (row < M) {
#pragma unroll
                    for (int j = 0; j < 8; ++j) {
                        const int col = nb + wn * 128 + j * 16 + lm;
                        float v = acc[i][j][r] + Cf[(size_t)row * ldc + col];
                        v = v > 0.f ? v : a * v;
                        acc[i][j][r] = v;
                        rss = fmaf(v, v, rss);
                    }
                }
                rss += __shfl_xor(rss, 1, 64);
                rss += __shfl_xor(rss, 2, 64);
                rss += __shfl_xor(rss, 4, 64);
                rss += __shfl_xor(rss, 8, 64);
                if (lm == 0 && row < M) shf[wave * 64 + rl] = rss;
            }
        __syncthreads();
#pragma unroll
        for (int i = 0; i < 4; ++i)
#pragma unroll
            for (int r = 0; r < 4; ++r) {
                const int rl  = i * 16 + lq * 4 + r;
                const int row = mb + wm * 64 + rl;
                if (row >= M) continue;
                const float tot = shf[wm * 64 + rl] + shf[(2 + wm) * 64 + rl];
                const float inv = 1.0f / fmaxf(sqrtf(tot), 1e-12f);
#pragma unroll
                for (int j = 0; j < 8; ++j) {
                    const int col = nb + wn * 128 + j * 16 + lm;
                    const float v = acc[i][j][r] * inv;
                    const _Float16 hi = (_Float16)v;
                    const size_t idx = (size_t)row * ldc + col;
                    Ohi[idx] = hi;
                    Olo[idx] = (_Float16)(v - (float)hi);
                }
            }
    }
}

// ================= CSR build: counting sort by key = rel*N_NODES + dst ======
__global__ __launch_bounds__(256) void hist_kernel(const int* __restrict__ dst,
                                                   const int* __restrict__ etype,
                                                   int* __restrict__ cnt) {
    const int e = blockIdx.x * 256 + threadIdx.x;
    if (e >= N_EDGES) return;
    atomicAdd(&cnt[etype[e] * N_NODES + dst[e]], 1);
}

__global__ __launch_bounds__(SCAN_T) void scan1_kernel(const int* __restrict__ cnt,
                                                       int* __restrict__ off,
                                                       int* __restrict__ bsum) {
    __shared__ int sh[SCAN_T];
    const int b = blockIdx.x, t = threadIdx.x;
    const int base = b * SCAN_CHUNK + t * SCAN_E;
    int pre[SCAN_E];
    int s = 0;
#pragma unroll
    for (int i = 0; i < SCAN_E; ++i) {
        const int x = (base + i < NKEYS) ? cnt[base + i] : 0;
        pre[i] = s;
        s += x;
    }
    sh[t] = s;
    __syncthreads();
    for (int d = 1; d < SCAN_T; d <<= 1) {
        const int x = (t >= d) ? sh[t - d] : 0;
        __syncthreads();
        sh[t] += x;
        __syncthreads();
    }
    const int toff = (t == 0) ? 0 : sh[t - 1];
#pragma unroll
    for (int i = 0; i < SCAN_E; ++i)
        if (base + i < NKEYS) off[base + i] = toff + pre[i];
    if (t == SCAN_T - 1) bsum[b] = sh[SCAN_T - 1];
}

__global__ __launch_bounds__(SCAN_T) void scan2_kernel(int* __restrict__ bsum, int n) {
    __shared__ int sh[SCAN_T];
    const int t = threadIdx.x;
    const int base = t * SCAN_E;
    int pre[SCAN_E];
    int s = 0;
#pragma unroll
    for (int i = 0; i < SCAN_E; ++i) {
        const int x = (base + i < n) ? bsum[base + i] : 0;
        pre[i] = s;
        s += x;
    }
    sh[t] = s;
    __syncthreads();
    for (int d = 1; d < SCAN_T; d <<= 1) {
        const int x = (t >= d) ? sh[t - d] : 0;
        __syncthreads();
        sh[t] += x;
        __syncthreads();
    }
    const int toff = (t == 0) ? 0 : sh[t - 1];
#pragma unroll
    for (int i = 0; i < SCAN_E; ++i)
        if (base + i < n) bsum[base + i] = toff + pre[i];
}

__global__ __launch_bounds__(SCAN_T) void scan3_kernel(int* __restrict__ off,
                                                       const int* __restrict__ bsum) {
    const int b = blockIdx.x, t = threadIdx.x;
    const int add = bsum[b];
    const int base = b * SCAN_CHUNK + t * SCAN_E;
#pragma unroll
    for (int i = 0; i < SCAN_E; ++i)
        if (base + i < NKEYS) off[base + i] += add;
    if (b == 0 && t == 0) off[NKEYS] = N_EDGES;
}

__global__ __launch_bounds__(256) void csr_fill_kernel(const int* __restrict__ src,
                                                       const int* __restrict__ dst,
                                                       const int* __restrict__ etype,
                                                       int* __restrict__ cursor,
                                                       int* __restrict__ sorted_src) {
    const int e = blockIdx.x * 256 + threadIdx.x;
    if (e >= N_EDGES) return;
    const int key = etype[e] * N_NODES + dst[e];
    const int pos = atomicAdd(&cursor[key], 1);
    sorted_src[pos] = src[e];
}

// ---------- aggregation: one wave per (node, rel); 4 edges/iteration --------
// half-wave h handles edges e0+h and e0+2+h; both indices loaded up front so
// 4 gathers are in flight per dependent round (bucket avg 2.67 edges -> ~1 round).
__global__ __launch_bounds__(256) void agg_kernel(const _Float16* __restrict__ Hhi,
                                                  const _Float16* __restrict__ Hlo,
                                                  const int* __restrict__ off,
                                                  const int* __restrict__ isrc,
                                                  _Float16* __restrict__ agghi,
                                                  _Float16* __restrict__ agglo,
                                                  int rel0, int nrel) {
    const int p    = blockIdx.x * 4 + (threadIdx.x >> 6);
    const int lane = threadIdx.x & 63;
    const int half = lane >> 5, li = lane & 31;
    if (p >= nrel * N_NODES) return;
    const int pl   = p / N_NODES;
    const int node = p - pl * N_NODES;
    const int r    = rel0 + pl;
    const int s0 = off[r * N_NODES + node];
    const int s1 = off[r * N_NODES + node + 1];
    float a[8] = {0.f, 0.f, 0.f, 0.f, 0.f, 0.f, 0.f, 0.f};
    for (int e0 = s0; e0 < s1; e0 += 4) {
        const int ea = e0 + half;
        const int eb = e0 + 2 + half;
        const int sa = (ea < s1) ? isrc[ea] : -1;
        const int sb = (eb < s1) ? isrc[eb] : -1;
        if (sa >= 0) {
            const h8 vh = *(const h8*)(Hhi + (size_t)sa * DD + li * 8);
            const h8 vl = *(const h8*)(Hlo + (size_t)sa * DD + li * 8);
#pragma unroll
            for (int k = 0; k < 8; ++k) a[k] += (float)vh[k] + (float)vl[k];
        }
        if (sb >= 0) {
            const h8 vh = *(const h8*)(Hhi + (size_t)sb * DD + li * 8);
            const h8 vl = *(const h8*)(Hlo + (size_t)sb * DD + li * 8);
#pragma unroll
            for (int k = 0; k < 8; ++k) a[k] += (float)vh[k] + (float)vl[k];
        }
    }
#pragma unroll
    for (int k = 0; k < 8; ++k) a[k] += __shfl_xor(a[k], 32, 64);
    if (half == 0) {
        h8 oh, ol;
#pragma unroll
        for (int k = 0; k < 8; ++k) {
            oh[k] = (_Float16)a[k];
            ol[k] = (_Float16)(a[k] - (float)oh[k]);
        }
        const size_t o = ((size_t)pl * N_NODES + node) * DD + li * 8;
        *(h8*)(agghi + o) = oh;
        *(h8*)(agglo + o) = ol;
    }
}

// ---------------- pooled[batch[n]] += hi[n]+lo[n]  (batch sorted) -----------
__global__ __launch_bounds__(64) void pool_kernel(const _Float16* __restrict__ ghi,
                                                  const _Float16* __restrict__ glo,
                                                  const int* __restrict__ batch,
                                                  float* __restrict__ pooled) {
    const int c     = threadIdx.x;
    const int start = blockIdx.x * 128;
    const int end   = min(start + 128, N_NODES);
    int cur = batch[start];
    float4 acc = {0.f, 0.f, 0.f, 0.f};
    for (int n = start; n < end; ++n) {
        const int bn = batch[n];
        if (bn != cur) {
            float* p = pooled + (size_t)cur * DD + c * 4;
            atomAddF(p + 0, acc.x); atomAddF(p + 1, acc.y);
            atomAddF(p + 2, acc.z); atomAddF(p + 3, acc.w);
            acc = {0.f, 0.f, 0.f, 0.f};
            cur = bn;
        }
        const h4 vh = *(const h4*)(ghi + (size_t)n * DD + c * 4);
        const h4 vl = *(const h4*)(glo + (size_t)n * DD + c * 4);
        acc.x += (float)vh[0] + (float)vl[0];
        acc.y += (float)vh[1] + (float)vl[1];
        acc.z += (float)vh[2] + (float)vl[2];
        acc.w += (float)vh[3] + (float)vl[3];
    }
    float* p = pooled + (size_t)cur * DD + c * 4;
    atomAddF(p + 0, acc.x); atomAddF(p + 1, acc.y);
    atomAddF(p + 2, acc.z); atomAddF(p + 3, acc.w);
}

// ---------------- out = relu((z2hi+z2lo) @ out_W + out_b) -------------------
__global__ __launch_bounds__(64) void out_kernel(const _Float16* __restrict__ z2hi,
                                                 const _Float16* __restrict__ z2lo,
                                                 const float* __restrict__ W,
                                                 const float* __restrict__ b,
                                                 float* __restrict__ out) {
    const int g = blockIdx.x;
    const int t = threadIdx.x;
    float s = 0.f;
#pragma unroll
    for (int j = 0; j < 8; ++j) {
        const int idx = t + 64 * j;
        const float z = (float)z2hi[(size_t)g * 512 + idx] + (float)z2lo[(size_t)g * 512 + idx];
        s = fmaf(z, W[idx], s);
    }
#pragma unroll
    for (int off = 32; off; off >>= 1) s += __shfl_xor(s, off, 64);
    if (t == 0) {
        const float v = s + b[0];
        out[g] = v > 0.f ? v : 0.f;
    }
}

extern "C" void kernel_launch(void* const* d_in, const int* in_sizes, int n_in,
                              void* d_out, int out_size, void* d_ws, size_t ws_size,
                              hipStream_t stream) {
    const float* x       = (const float*)d_in[0];
    const int*   eidx    = (const int*)d_in[1];
    const int*   etype   = (const int*)d_in[2];
    const int*   batch   = (const int*)d_in[3];
    const float* enc_W   = (const float*)d_in[4];
    const float* enc_b   = (const float*)d_in[5];
    const float* prelu_a = (const float*)d_in[6];
    const float* rel_W   = (const float*)d_in[7];
    const float* root_W  = (const float*)d_in[8];
    const float* conv_b  = (const float*)d_in[9];
    const float* gp_W1   = (const float*)d_in[10];
    const float* gp_b1   = (const float*)d_in[11];
    const float* gp_W2   = (const float*)d_in[12];
    const float* gp_b2   = (const float*)d_in[13];
    const float* fc_W1   = (const float*)d_in[14];
    const float* fc_b1   = (const float*)d_in[15];
    const float* fc_W2   = (const float*)d_in[16];
    const float* fc_b2   = (const float*)d_in[17];
    const float* out_W   = (const float*)d_in[18];
    const float* out_b   = (const float*)d_in[19];
    float* out = (float*)d_out;

    // workspace arena — HARD BUDGET: 236 MB ran (R8), 277 MB crashed (R4/R9).
    // Sum here: 51.2+25.6+25.6+51.2+51.2+7.3+7.3+0.26x4+0.5+1x2+0.26+0.05x2
    //           +1x2+0.5x2+1.2+1.2+0.001+3.2 ≈ 233 MB. OK.
    uint8_t* wp = (uint8_t*)d_ws;
    auto alloc = [&](size_t bytes) {
        void* r = (void*)wp;
        wp += (bytes + 255) & ~(size_t)255;
        return r;
    };
    float*    base   = (float*)alloc((size_t)N_NODES * DD * 4);          // 51.2 MB
    _Float16* Hhi    = (_Float16*)alloc((size_t)N_NODES * DD * 2);       // 25.6 MB
    _Float16* Hlo    = (_Float16*)alloc((size_t)N_NODES * DD * 2);       // 25.6 MB
    _Float16* agghi  = (_Float16*)alloc((size_t)2 * N_NODES * DD * 2);   // 51.2 MB (2 planes)
    _Float16* agglo  = (_Float16*)alloc((size_t)2 * N_NODES * DD * 2);   // 51.2 MB
    _Float16* wthi   = (_Float16*)alloc((size_t)N_LAYERS * 256 * 1792 * 2);  // 7.3 MB
    _Float16* wtlo   = (_Float16*)alloc((size_t)N_LAYERS * 256 * 1792 * 2);  // 7.3 MB
    _Float16* wtg1hi = (_Float16*)alloc((size_t)256 * 256 * 2);
    _Float16* wtg1lo = (_Float16*)alloc((size_t)256 * 256 * 2);
    _Float16* wtg2hi = (_Float16*)alloc((size_t)256 * 256 * 2);
    _Float16* wtg2lo = (_Float16*)alloc((size_t)256 * 256 * 2);
    _Float16* wtf1hi = (_Float16*)alloc((size_t)1024 * 256 * 2);
    _Float16* wtf1lo = (_Float16*)alloc((size_t)1024 * 256 * 2);
    _Float16* wtf2hi = (_Float16*)alloc((size_t)512 * 1024 * 2);
    _Float16* wtf2lo = (_Float16*)alloc((size_t)512 * 1024 * 2);
    float*    pooled = (float*)alloc((size_t)NUM_GRAPHS * DD * 4);
    _Float16* phi    = (_Float16*)alloc((size_t)NUM_GRAPHS * DD * 2);
    _Float16* plo    = (_Float16*)alloc((size_t)NUM_GRAPHS * DD * 2);
    _Float16* z1hi   = (_Float16*)alloc((size_t)NUM_GRAPHS * 1024 * 2);
    _Float16* z1lo   = (_Float16*)alloc((size_t)NUM_GRAPHS * 1024 * 2);
    _Float16* z2hi   = (_Float16*)alloc((size_t)NUM_GRAPHS * 512 * 2);
    _Float16* z2lo   = (_Float16*)alloc((size_t)NUM_GRAPHS * 512 * 2);
    int*      ioff   = (int*)alloc((size_t)(NKEYS + 1) * 4);
    int*      icur   = (int*)alloc((size_t)NKEYS * 4);
    int*      ibsum  = (int*)alloc(256 * 4);
    int*      isrc   = (int*)alloc((size_t)N_EDGES * 4);

    const int* src = eidx;
    const int* dst = eidx + N_EDGES;

    // ---- weight prep ----
    const size_t wtot = (size_t)N_LAYERS * 7 * 256 * 256;
    wsplit_rel_kernel<<<(int)((wtot + 255) / 256), 256, 0, stream>>>(rel_W, root_W, wthi, wtlo);
    wsplit_tr_kernel<<<256, 256, 0, stream>>>(gp_W1, wtg1hi, wtg1lo, 256, 256);
    wsplit_tr_kernel<<<256, 256, 0, stream>>>(gp_W2, wtg2hi, wtg2lo, 256, 256);
    wsplit_tr_kernel<<<1024, 256, 0, stream>>>(fc_W1, wtf1hi, wtf1lo, 256, 1024);
    wsplit_tr_kernel<<<2048, 256, 0, stream>>>(fc_W2, wtf2hi, wtf2lo, 1024, 512);

    // ---- CSR build ----
    hipMemsetAsync(icur, 0, (size_t)NKEYS * sizeof(int), stream);
    const int eb = (N_EDGES + 255) / 256;
    hist_kernel<<<eb, 256, 0, stream>>>(dst, etype, icur);
    scan1_kernel<<<SCAN_NB, SCAN_T, 0, stream>>>(icur, ioff, ibsum);
    scan2_kernel<<<1, SCAN_T, 0, stream>>>(ibsum, SCAN_NB);
    scan3_kernel<<<SCAN_NB, SCAN_T, 0, stream>>>(ioff, ibsum);
    hipMemcpyAsync(icur, ioff, (size_t)NKEYS * sizeof(int), hipMemcpyDeviceToDevice, stream);
    csr_fill_kernel<<<eb, 256, 0, stream>>>(src, dst, etype, icur, isrc);

    // ---- encoder ----
    enc_kernel<<<N_NODES, 256, 0, stream>>>(x, enc_W, enc_b, Hhi, Hlo);

    const dim3 gG((N_NODES + 127) / 128, 1);  // 391 x 1 — R8-proven tile/grid
    const int  aggb = (2 * N_NODES + 3) / 4;  // 2 rels per agg pass

    for (int L = 0; L < N_LAYERS; ++L) {
        const _Float16* Bh = wthi + (size_t)L * 256 * 1792;
        const _Float16* Bl = wtlo + (size_t)L * 256 * 1792;
        // GEMM1: rels 0,1 (K_agg=512) + h seg (root+I, K=256) + conv_b -> base
        agg_kernel<<<aggb, 256, 0, stream>>>(Hhi, Hlo, ioff, isrc, agghi, agglo, 0, 2);
        gemm_lds<0><<<gG, 256, 0, stream>>>(agghi, agglo, Hhi, Hlo, Bh, Bl,
                                            256, 1792, 256, 0, 1536, 512, 768,
                                            base, nullptr, nullptr,
                                            conv_b + L * DD, nullptr, N_NODES);
        // GEMM2: rels 2,3 accumulate into base
        agg_kernel<<<aggb, 256, 0, stream>>>(Hhi, Hlo, ioff, isrc, agghi, agglo, 2, 2);
        gemm_lds<3><<<gG, 256, 0, stream>>>(agghi, agglo, nullptr, nullptr, Bh, Bl,
                                            256, 1792, 256, 512, 0, 512, 512,
                                            base, nullptr, nullptr,
                                            nullptr, nullptr, N_NODES);
        // GEMM3: rels 4,5 + base; fused PReLU + full-row L2-norm -> new h
        agg_kernel<<<aggb, 256, 0, stream>>>(Hhi, Hlo, ioff, isrc, agghi, agglo, 4, 2);
        gemm_lds<1><<<gG, 256, 0, stream>>>(agghi, agglo, nullptr, nullptr, Bh, Bl,
                                            256, 1792, 256, 1024, 0, 512, 512,
                                            base, Hhi, Hlo,
                                            nullptr, prelu_a, N_NODES);
    }

    // gp1 = relu(h @ gp_W1 + gp_b1) -> planes (agg plane 0)
    gemm_lds<2><<<gG, 256, 0, stream>>>(nullptr, nullptr, Hhi, Hlo, wtg1hi, wtg1lo,
                                        256, 256, 256, 0, 0, 0, 256,
                                        nullptr, agghi, agglo, gp_b1, nullptr, N_NODES);
    // gp2 = gp1 @ gp_W2 + gp_b2 -> planes (agg plane 1)
    gemm_lds<4><<<gG, 256, 0, stream>>>(agghi, agglo, nullptr, nullptr, wtg2hi, wtg2lo,
                                        256, 256, 256, 0, 0, 256, 256,
                                        nullptr, agghi + (size_t)N_NODES * DD,
                                        agglo + (size_t)N_NODES * DD, gp_b2, nullptr, N_NODES);

    hipMemsetAsync(pooled, 0, (size_t)NUM_GRAPHS * DD * sizeof(float), stream);
    pool_kernel<<<(N_NODES + 127) / 128, 64, 0, stream>>>(
        agghi + (size_t)N_NODES * DD, agglo + (size_t)N_NODES * DD, batch, pooled);
    fsplit_kernel<<<(NUM_GRAPHS * DD + 255) / 256, 256, 0, stream>>>(
        pooled, phi, plo, NUM_GRAPHS * DD);

    // z1 = relu(pooled @ fc_W1 + fc_b1): M=512, K=256, N=1024
    gemm_lds<2><<<dim3(4, 4), 256, 0, stream>>>(nullptr, nullptr, phi, plo, wtf1hi, wtf1lo,
                                                256, 256, 1024, 0, 0, 0, 256,
                                                nullptr, z1hi, z1lo, fc_b1, nullptr,
                                                NUM_GRAPHS);
    // z2 = relu(z1 @ fc_W2 + fc_b2): M=512, K=1024, N=512
    gemm_lds<2><<<dim3(4, 2), 256, 0, stream>>>(nullptr, nullptr, z1hi, z1lo, wtf2hi, wtf2lo,
                                                1024, 1024, 512, 0, 0, 0, 1024,
                                                nullptr, z2hi, z2lo, fc_b2, nullptr,
                                                NUM_GRAPHS);
    out_kernel<<<NUM_GRAPHS, 64, 0, stream>>>(z2hi, z2lo, out_W, out_b, out);
}